// Round 6
// baseline (6631.124 us; speedup 1.0000x reference)
//
#include <hip/hip_runtime.h>
#include <hip/hip_bf16.h>

// bidirLSTM: T=8192, V=1e6, E=60, D=60, C=5. fp32 in/out, tokens int32.
//
// R6: R5's single-wave scan + NO ALLOCAS in hot code.
//   R2-R5 post-mortem: every per-lane weight array (wh[60], whg[4][16],
//   w2[4][30]) was demoted to SCRATCH (VGPR_Count 44/144 << needed), so the
//   serial loop reloaded weights from memory every step. Fix: weights live
//   in 60 macro-named v4f SSA values (SSA can't be scratch-demoted; ~300
//   VGPRs < 512 budget at launch_bounds(64,1)). v2f elementwise fma ->
//   v_pk_fma_f32. Same fix in gates_kernel (15 named v4f).

#define T_LEN 8192
#define E_DIM 60
#define D_DIM 60
#define TB    32

typedef float v2f __attribute__((ext_vector_type(2)));
typedef float v4f __attribute__((ext_vector_type(4)));

__device__ __forceinline__ float fast_rcp(float x) { return __builtin_amdgcn_rcpf(x); }
__device__ __forceinline__ v2f lo2(v4f v) { return __builtin_shufflevector(v, v, 0, 1); }
__device__ __forceinline__ v2f hi2(v4f v) { return __builtin_shufflevector(v, v, 2, 3); }

#define REPI15(M) M(0) M(1) M(2) M(3) M(4) M(5) M(6) M(7) M(8) M(9) M(10) M(11) M(12) M(13) M(14)

// ---------------------------------------------------------------------------
// Kernel 1: gxp[(dir*T+t)*256 + p], p = dd*4+gate  (unit dd's 4 gates are one
// contiguous float4 = the scan's per-lane dwordx4).
// ---------------------------------------------------------------------------
__global__ __launch_bounds__(256) void gates_kernel(
    const int*   __restrict__ tokens,
    const float* __restrict__ emb,
    const float* __restrict__ WxhL,
    const float* __restrict__ bxhL,
    const float* __restrict__ bhhL,
    const float* __restrict__ WxhR,
    const float* __restrict__ bxhR,
    const float* __restrict__ bhhR,
    float* __restrict__ gxp)
{
    const int dir = blockIdx.y;
    const float* Wxh = dir ? WxhR : WxhL;
    const float* bxh = dir ? bxhR : bxhL;
    const float* bhh = dir ? bhhR : bhhL;

    const int p = threadIdx.x;
    const int gate = p & 3;
    const int dd = p >> 2;                // 0..63
    const bool act = (dd < D_DIM);
    const int j = gate * 60 + (act ? dd : 0);

    const v4f zf4 = {0.f, 0.f, 0.f, 0.f};
    const float* rp = Wxh + (size_t)j * E_DIM;   // 240 B stride, 16B-aligned

    // 15 named v4f weights — SSA, never scratch.
#define DECLX(i) v4f wx##i = act ? *(const v4f*)(rp + 4 * (i)) : zf4;
    REPI15(DECLX)
#undef DECLX
    const float bj = act ? (bxh[j] + bhh[j]) : 0.f;

    __shared__ __align__(16) float xs[64];
    const v4f* xb4 = (const v4f*)xs;
    const int t0 = blockIdx.x * TB;
    for (int tt = 0; tt < TB; ++tt) {
        const int t = t0 + tt;
        const int idx = dir ? (T_LEN - 1 - t) : t;
        const int tok = tokens[idx];
        if (p < 15) {
            v4f v = *(const v4f*)(emb + (size_t)tok * E_DIM + 4 * p);
            *((v4f*)xs + p) = v;
        }
        __syncthreads();

        v2f sl = {bj, 0.f}, sh = {0.f, 0.f};
#define FMAX(i) { v4f xv = xb4[i]; \
        sl = __builtin_elementwise_fma(lo2(wx##i), lo2(xv), sl); \
        sh = __builtin_elementwise_fma(hi2(wx##i), hi2(xv), sh); }
        REPI15(FMAX)
#undef FMAX
        gxp[((size_t)dir * T_LEN + t) * 256 + p] = (sl.x + sl.y) + (sh.x + sh.y);
        __syncthreads();
    }
}

// ---------------------------------------------------------------------------
// Kernel 2: sequential scan. grid = 2 (dir), block = 64 (ONE wave).
// ---------------------------------------------------------------------------
__global__ __launch_bounds__(64, 1) void scan_kernel(
    const float* __restrict__ WhhL,
    const float* __restrict__ WhhR,
    const float* __restrict__ gxp,
    float* __restrict__ hout)
{
    const int dir = blockIdx.x;
    const float* Whh = dir ? WhhR : WhhL;

    const int dd = threadIdx.x;           // lane == hidden unit
    const bool actv = (dd < D_DIM);
    const int du = actv ? dd : 0;

    const v4f zf4 = {0.f, 0.f, 0.f, 0.f};
    const float* rp0 = Whh + (size_t)(0 * 60 + du) * D_DIM;
    const float* rp1 = Whh + (size_t)(1 * 60 + du) * D_DIM;
    const float* rp2 = Whh + (size_t)(2 * 60 + du) * D_DIM;
    const float* rp3 = Whh + (size_t)(3 * 60 + du) * D_DIM;

    // 60 named v4f = 240 VGPRs of weights — SSA, never scratch.
#define DECLW(i) \
    v4f w0_##i = actv ? *(const v4f*)(rp0 + 4 * (i)) : zf4; \
    v4f w1_##i = actv ? *(const v4f*)(rp1 + 4 * (i)) : zf4; \
    v4f w2_##i = actv ? *(const v4f*)(rp2 + 4 * (i)) : zf4; \
    v4f w3_##i = actv ? *(const v4f*)(rp3 + 4 * (i)) : zf4;
    REPI15(DECLW)
#undef DECLW

    __shared__ __align__(16) float hbuf[64];
    hbuf[dd] = 0.f;                       // single wave: no barrier needed
    const v4f* hb4 = (const v4f*)hbuf;

    float c = 0.f, hmine = 0.f;
    const float4* G = (const float4*)gxp + (size_t)dir * T_LEN * 64 + dd;

    // prefetch ring depth 4; address-clamped (value never consumed past end)
    float4 r0 = G[0];
    float4 r1 = G[64];
    float4 r2 = G[2 * 64];
    float4 r3 = G[3 * 64];

    for (int t = 0; t < T_LEN; ++t) {
        const float4 gx = r0;
        r0 = r1; r1 = r2; r2 = r3;
        const int tp = (t + 4 < T_LEN) ? (t + 4) : (T_LEN - 1);
        r3 = G[(size_t)tp * 64];

        v2f a0l = {gx.x, 0.f}, a0h = {0.f, 0.f};
        v2f a1l = {gx.y, 0.f}, a1h = {0.f, 0.f};
        v2f a2l = {gx.z, 0.f}, a2h = {0.f, 0.f};
        v2f a3l = {gx.w, 0.f}, a3h = {0.f, 0.f};

#define FMACH(i) { v4f hv = hb4[i]; v2f hl = lo2(hv), hh = hi2(hv); \
        a0l = __builtin_elementwise_fma(lo2(w0_##i), hl, a0l); \
        a0h = __builtin_elementwise_fma(hi2(w0_##i), hh, a0h); \
        a1l = __builtin_elementwise_fma(lo2(w1_##i), hl, a1l); \
        a1h = __builtin_elementwise_fma(hi2(w1_##i), hh, a1h); \
        a2l = __builtin_elementwise_fma(lo2(w2_##i), hl, a2l); \
        a2h = __builtin_elementwise_fma(hi2(w2_##i), hh, a2h); \
        a3l = __builtin_elementwise_fma(lo2(w3_##i), hl, a3l); \
        a3h = __builtin_elementwise_fma(hi2(w3_##i), hh, a3h); }
        REPI15(FMACH)
#undef FMACH

        const float g0 = (a0l.x + a0l.y) + (a0h.x + a0h.y);   // i
        const float g1 = (a1l.x + a1l.y) + (a1h.x + a1h.y);   // f
        const float g2 = (a2l.x + a2l.y) + (a2h.x + a2h.y);   // cg
        const float g3 = (a3l.x + a3l.y) + (a3h.x + a3h.y);   // o

        const float i_ = fast_rcp(1.f + __expf(-g0));
        const float f_ = fast_rcp(1.f + __expf(-g1));
        const float cg = 1.f - 2.f * fast_rcp(__expf(2.f * g2) + 1.f);
        const float o_ = fast_rcp(1.f + __expf(-g3));

        c = f_ * c + i_ * cg;
        const float th = 1.f - 2.f * fast_rcp(__expf(2.f * c) + 1.f);
        hmine = o_ * th;

        hbuf[dd] = actv ? hmine : 0.f;    // same-wave ordering via lgkmcnt
    }

    if (actv) hout[dir * 64 + dd] = hmine;
}

// ---------------------------------------------------------------------------
// Kernel 3: out[c] = Why_L[c,:] @ h_L + Why_R[c,:] @ h_R
// ---------------------------------------------------------------------------
__global__ __launch_bounds__(64) void out_kernel(
    const float* __restrict__ WhyL,
    const float* __restrict__ WhyR,
    const float* __restrict__ hout,
    float* __restrict__ out)
{
    const int cI = threadIdx.x;
    if (cI < 5) {
        float s = 0.f;
        #pragma unroll
        for (int d = 0; d < D_DIM; ++d) {
            s += WhyL[cI * D_DIM + d] * hout[d];
            s += WhyR[cI * D_DIM + d] * hout[64 + d];
        }
        out[cI] = s;
    }
}

extern "C" void kernel_launch(void* const* d_in, const int* in_sizes, int n_in,
                              void* d_out, int out_size, void* d_ws, size_t ws_size,
                              hipStream_t stream) {
    const int*   tokens = (const int*)d_in[0];
    const float* emb    = (const float*)d_in[1];
    const float* WxhL   = (const float*)d_in[2];
    const float* WhhL   = (const float*)d_in[3];
    const float* bxhL   = (const float*)d_in[4];
    const float* bhhL   = (const float*)d_in[5];
    const float* WxhR   = (const float*)d_in[6];
    const float* WhhR   = (const float*)d_in[7];
    const float* bxhR   = (const float*)d_in[8];
    const float* bhhR   = (const float*)d_in[9];
    const float* WhyL   = (const float*)d_in[10];
    const float* WhyR   = (const float*)d_in[11];

    float* gxp  = (float*)d_ws;                       // 2*8192*256 floats = 16 MB
    float* hout = gxp + (size_t)2 * T_LEN * 256;      // 128 floats

    dim3 g1(T_LEN / TB, 2);
    gates_kernel<<<g1, 256, 0, stream>>>(tokens, emb, WxhL, bxhL, bhhL,
                                         WxhR, bxhR, bhhR, gxp);
    scan_kernel<<<2, 64, 0, stream>>>(WhhL, WhhR, gxp, hout);
    out_kernel<<<1, 64, 0, stream>>>(WhyL, WhyR, hout, (float*)d_out);
}